// Round 8
// baseline (835.350 us; speedup 1.0000x reference)
//
#include <hip/hip_runtime.h>
#include <stdint.h>

typedef unsigned short u16;
typedef __attribute__((ext_vector_type(4))) float f32x4;
typedef __attribute__((ext_vector_type(8))) short s16x8;
typedef __attribute__((ext_vector_type(4))) short s16x4;

#define DD (512*512)

__device__ inline u16 f2bf(float f) {
  uint32_t u = __float_as_uint(f);
  u = (u + 0x7FFFu + ((u >> 16) & 1u)) >> 16;
  return (u16)u;
}
__device__ inline float bflo(uint32_t w) { return __uint_as_float(w << 16); }
__device__ inline float bfhi(uint32_t w) { return __uint_as_float(w & 0xFFFF0000u); }
__device__ inline f32x4 relu4(f32x4 v) {
  f32x4 r;
  r.x = fmaxf(v.x, 0.f); r.y = fmaxf(v.y, 0.f);
  r.z = fmaxf(v.z, 0.f); r.w = fmaxf(v.w, 0.f);
  return r;
}
__device__ inline f32x4 bf4(const u16* p) {
  uint2 w = *(const uint2*)p;
  f32x4 r; r.x = bflo(w.x); r.y = bfhi(w.x); r.z = bflo(w.y); r.w = bfhi(w.y);
  return r;
}
__device__ inline s16x4 pack4(f32x4 v) {
  s16x4 o;
  o[0] = (short)f2bf(v.x); o[1] = (short)f2bf(v.y);
  o[2] = (short)f2bf(v.z); o[3] = (short)f2bf(v.w);
  return o;
}
__device__ inline void gload16(const void* g, void* l) {
  __builtin_amdgcn_global_load_lds(
      (const __attribute__((address_space(1))) void*)g,
      (__attribute__((address_space(3))) void*)l, 16, 0, 0);
}

// ================= kprep: ktotl1 + kcast(rw2) + kwcast(cw) + kmisc + kH fused =================
struct PrepP {
  const float *xo, *xw, *xf;
  const float *ow1, *ob1, *ww1, *wb1, *fw1, *fb1;
  float* hid;
  const float* rw2; u16* rw2b;
  const float* cw; u16* cwT;
  const float* cb; const float* rb2;
  float *b0b, *b0p, *b1b, *b1p;
  const float *xr, *rw1, *rb1; u16* Hh;
};

__global__ __launch_bounds__(256) void kprep(PrepP pp) {
  __shared__ __align__(16) float plds[1088];
  const int bid = blockIdx.x;
  const int t = threadIdx.x;
  if (bid < 209) {
    int tc = bid;
    const float* x; const float* w; const float* b; int K;
    if (tc < 192)      { x = pp.xo + tc * 42;         w = pp.ow1; b = pp.ob1; K = 42; }
    else if (tc < 208) { x = pp.xw + (tc - 192) * 15; w = pp.ww1; b = pp.wb1; K = 15; }
    else               { x = pp.xf;                   w = pp.fw1; b = pp.fb1; K = 16; }
    float* xs = plds;
    if (t < K) xs[t] = x[t];
    __syncthreads();
    #pragma unroll
    for (int dd = 0; dd < 2; dd++) {
      int d = t + dd * 256;
      float acc = b[d];
      for (int k = 0; k < K; k++) acc = fmaf(xs[k], w[k * 512 + d], acc);
      pp.hid[(size_t)tc * 512 + d] = fmaxf(acc, 0.f);
    }
  } else if (bid < 337) {
    int g = (bid - 209) * 256 + t;
    f32x4 a = *(const f32x4*)&pp.rw2[(size_t)g * 8];
    f32x4 b = *(const f32x4*)&pp.rw2[(size_t)g * 8 + 4];
    s16x8 o;
    o[0] = (short)f2bf(a.x); o[1] = (short)f2bf(a.y); o[2] = (short)f2bf(a.z); o[3] = (short)f2bf(a.w);
    o[4] = (short)f2bf(b.x); o[5] = (short)f2bf(b.y); o[6] = (short)f2bf(b.z); o[7] = (short)f2bf(b.w);
    *(s16x8*)&pp.rw2b[(size_t)g * 8] = o;
  } else if (bid < 1617) {
    int local = bid - 337;
    int bx = local & 15, by = (local >> 4) & 15, bz = local >> 8;
    float (*tile)[33] = (float(*)[33])plds;
    const float* src = pp.cw + (size_t)bz * DD;
    int k0 = bx * 32, n0 = by * 32;
    #pragma unroll
    for (int i = 0; i < 4; i++) {
      int idx = t + i * 256; int r = idx >> 5, c = idx & 31;
      tile[r][c] = src[(size_t)(k0 + r) * 512 + n0 + c];
    }
    __syncthreads();
    #pragma unroll
    for (int i = 0; i < 4; i++) {
      int idx = t + i * 256; int r = idx >> 5, c = idx & 31;
      pp.cwT[((size_t)bz * 512 + n0 + r) * 512 + k0 + c] = f2bf(tile[c][r]);
    }
  } else if (bid < 1625) {
    int bx = bid - 1617;
    int dl = t & 63;
    int d = bx * 64 + dl;
    int kg = t >> 6;
    const float* W0 = pp.cw;
    const float* W1 = pp.cw + DD;
    float a0 = 0, p0 = 0, a1 = 0, p1 = 0;
    for (int k = kg * 128; k < (kg + 1) * 128; ++k) {
      float w0 = W0[(size_t)k * 512 + d], w1 = W1[(size_t)k * 512 + d], r = pp.rb2[k];
      a0 = fmaf(r, w0, a0); p0 += w0;
      a1 = fmaf(r, w1, a1); p1 += w1;
    }
    float (*red)[4][64] = (float(*)[4][64])plds;
    red[0][kg][dl] = a0; red[1][kg][dl] = p0; red[2][kg][dl] = a1; red[3][kg][dl] = p1;
    __syncthreads();
    if (kg == 0) {
      float s0  = red[0][0][dl] + red[0][1][dl] + red[0][2][dl] + red[0][3][dl];
      float sp0 = red[1][0][dl] + red[1][1][dl] + red[1][2][dl] + red[1][3][dl];
      float s1  = red[2][0][dl] + red[2][1][dl] + red[2][2][dl] + red[2][3][dl];
      float sp1 = red[3][0][dl] + red[3][1][dl] + red[3][2][dl] + red[3][3][dl];
      float bb0 = pp.cb[0 * 512 + d], bb1 = pp.cb[1 * 512 + d];
      pp.b0b[d] = s0 + bb0;
      pp.b0p[d] = 0.001f * sp0 + bb0;
      pp.b1b[d] = s1 + bb1;
      pp.b1p[d] = 0.001f * sp1 + bb1;
    }
  } else {
    int gid = (bid - 1625) * 256 + t;
    int m = gid >> 6;
    int dg = (gid & 63) * 8;
    float x0 = pp.xr[m * 2], x1 = pp.xr[m * 2 + 1];
    s16x8 o;
    #pragma unroll
    for (int j = 0; j < 8; j++) {
      int dd = dg + j;
      float v = fmaf(x0, pp.rw1[dd], fmaf(x1, pp.rw1[512 + dd], pp.rb1[dd]));
      o[j] = (short)f2bf(fmaxf(v, 0.f));
    }
    *(s16x8*)&pp.Hh[(size_t)m * 512 + dg] = o;
  }
}

// ================= kmid: ksmall-pre (fp32 tot layer2) + kmg-pre (rw2b @ cwT -> WcT^T) fused ====
struct SJob { const float* A; const float* B; const float* bias; float* C; u16* Cb; int M; int act; };
struct SJobs { SJob j[4]; int cum[5]; int njobs; };
struct PMJob { const u16* A; const u16* BT; u16* W; };   // W: bf16 [n][k] transposed dest
struct MidP { SJobs sj; PMJob mj[2]; };

__global__ __launch_bounds__(256) void kmid(MidP mp) {
  __shared__ __align__(16) u16 mlds[24576];   // 48 KB
  const int t = threadIdx.x;
  if (blockIdx.x < 64) {
    // ---------- ksmall fp32 GEMM ----------
    int bi = blockIdx.x;
    int ji = 0;
    while (ji + 1 < mp.sj.njobs && bi >= mp.sj.cum[ji + 1]) ji++;
    SJob job = mp.sj.j[ji];
    int local = bi - mp.sj.cum[ji];
    int mt = local >> 3, nt = local & 7;
    int m0 = mt * 32, n0 = nt * 64;
    float* As = (float*)mlds;
    float* Bs = As + 32 * 36;
    int row = t >> 3;
    int cg  = (t & 7) * 8;
    f32x4 accA = {0.f,0.f,0.f,0.f}, accB = {0.f,0.f,0.f,0.f};
    for (int k0 = 0; k0 < 512; k0 += 32) {
      __syncthreads();
      {
        int ar = t >> 3, ac = (t & 7) * 4;
        f32x4 av = {0.f,0.f,0.f,0.f};
        if (m0 + ar < job.M) av = *(const f32x4*)&job.A[(size_t)(m0 + ar) * 512 + k0 + ac];
        *(f32x4*)&As[ar * 36 + ac] = av;
      }
      #pragma unroll
      for (int i = 0; i < 2; i++) {
        int idx = t + i * 256;
        int bk = idx >> 4, bn = (idx & 15) * 4;
        *(f32x4*)&Bs[bk * 64 + bn] = *(const f32x4*)&job.B[(size_t)(k0 + bk) * 512 + n0 + bn];
      }
      __syncthreads();
      #pragma unroll
      for (int kk = 0; kk < 32; kk += 4) {
        f32x4 a4 = *(const f32x4*)&As[row * 36 + kk];
        #pragma unroll
        for (int q = 0; q < 4; q++) {
          f32x4 b0 = *(const f32x4*)&Bs[(kk + q) * 64 + cg];
          f32x4 b1 = *(const f32x4*)&Bs[(kk + q) * 64 + cg + 4];
          float av = a4[q];
          accA += av * b0;
          accB += av * b1;
        }
      }
    }
    int r = m0 + row;
    if (r < job.M) {
      f32x4 b0 = {0.f,0.f,0.f,0.f}, b1 = {0.f,0.f,0.f,0.f};
      if (job.bias) { b0 = *(const f32x4*)&job.bias[n0 + cg]; b1 = *(const f32x4*)&job.bias[n0 + cg + 4]; }
      f32x4 o0 = accA + b0, o1 = accB + b1;
      if (job.act) { o0 = relu4(o0); o1 = relu4(o1); }
      *(f32x4*)&job.C[(size_t)r * 512 + n0 + cg]     = o0;
      *(f32x4*)&job.C[(size_t)r * 512 + n0 + cg + 4] = o1;
      if (job.Cb) {
        s16x8 ob;
        ob[0] = (short)f2bf(o0.x); ob[1] = (short)f2bf(o0.y);
        ob[2] = (short)f2bf(o0.z); ob[3] = (short)f2bf(o0.w);
        ob[4] = (short)f2bf(o1.x); ob[5] = (short)f2bf(o1.y);
        ob[6] = (short)f2bf(o1.z); ob[7] = (short)f2bf(o1.w);
        *(s16x8*)&job.Cb[(size_t)r * 512 + n0 + cg] = ob;
      }
    }
  } else {
    // ---------- kmg-pre: 512x512x512 bf16 MFMA, BM=64 BN=128 BK=64 dbuf; writes WcT transposed ----
    int bi = blockIdx.x - 64;
    int ji = bi >> 5;
    int local = bi & 31;
    PMJob job = mp.mj[ji];
    int m0 = (local >> 2) * 64, n0 = (local & 3) * 128;
    u16* smem = mlds;
    const int lane = t & 63;
    const int wave = t >> 6;
    const int wm = wave >> 1, wn = wave & 1;
    const int r16 = lane & 15;
    const int kq = lane >> 4;
    f32x4 acc[2][4];
    #pragma unroll
    for (int i = 0; i < 2; i++)
      #pragma unroll
      for (int j = 0; j < 4; j++) acc[i][j] = (f32x4){0.f,0.f,0.f,0.f};
    const u16* gA[2]; int laofs[2];
    const u16* gB[4]; int lbofs[4];
    #pragma unroll
    for (int i = 0; i < 2; i++) {
      int seg = i * 256 + t;
      int row = seg >> 3, s = seg & 7;
      gA[i] = job.A + (size_t)(m0 + row) * 512 + ((s ^ (row & 7)) << 3);
      laofs[i] = (i * 256 + (t & 192)) << 3;
    }
    #pragma unroll
    for (int i = 0; i < 4; i++) {
      int seg = i * 256 + t;
      int row = seg >> 3, s = seg & 7;
      gB[i] = job.BT + (size_t)(n0 + row) * 512 + ((s ^ (row & 7)) << 3);
      lbofs[i] = 4096 + ((i * 256 + (t & 192)) << 3);
    }
    #pragma unroll
    for (int i = 0; i < 2; i++) gload16(gA[i], smem + laofs[i]);
    #pragma unroll
    for (int i = 0; i < 4; i++) gload16(gB[i], smem + lbofs[i]);
    __syncthreads();
    int buf = 0;
    for (int it = 0; it < 8; ++it) {
      if (it < 7) {
        int nb = (buf ^ 1) * 12288;
        int k0n = (it + 1) * 64;
        #pragma unroll
        for (int i = 0; i < 2; i++) gload16(gA[i] + k0n, smem + nb + laofs[i]);
        #pragma unroll
        for (int i = 0; i < 4; i++) gload16(gB[i] + k0n, smem + nb + lbofs[i]);
      }
      const u16* Ab = smem + buf * 12288;
      const u16* Bb = Ab + 4096;
      #pragma unroll
      for (int kh = 0; kh < 2; kh++) {
        s16x8 af[2], bfr[4];
        #pragma unroll
        for (int i = 0; i < 2; i++) {
          int r = wm * 32 + i * 16 + r16;
          af[i] = *(const s16x8*)&Ab[r * 64 + (((kq + kh * 4) ^ (r & 7)) << 3)];
        }
        #pragma unroll
        for (int j = 0; j < 4; j++) {
          int r = wn * 64 + j * 16 + r16;
          bfr[j] = *(const s16x8*)&Bb[r * 64 + (((kq + kh * 4) ^ (r & 7)) << 3)];
        }
        #pragma unroll
        for (int i = 0; i < 2; i++)
          #pragma unroll
          for (int j = 0; j < 4; j++)
            acc[i][j] = __builtin_amdgcn_mfma_f32_16x16x32_bf16(af[i], bfr[j], acc[i][j], 0, 0, 0);
      }
      __syncthreads();
      buf ^= 1;
    }
    // epilogue: write transposed bf16 directly into WcT slab: W[col][k]
    #pragma unroll
    for (int i = 0; i < 2; i++) {
      int rbase = m0 + wm * 32 + i * 16 + kq * 4;   // k index base
      #pragma unroll
      for (int j = 0; j < 4; j++) {
        int col = n0 + wn * 64 + j * 16 + r16;      // n index
        s16x4 o;
        #pragma unroll
        for (int r = 0; r < 4; r++) o[r] = (short)f2bf(acc[i][j][r]);
        *(s16x4*)&job.W[(size_t)col * 512 + rbase] = o;
      }
    }
  }
}

// ================= kbig: Q = H(36864x512) @ WcT^T -> Q0/Q1T, XCD-aware mapping =================
__global__ __launch_bounds__(256) void kbig(const u16* __restrict__ Hh, const u16* __restrict__ WcT,
                                            u16* __restrict__ Q0, u16* __restrict__ Q1T) {
  __shared__ u16 smem[2 * 16384];   // 64 KB dbuf
  const int bid = blockIdx.x;
  const int xcd = bid & 7;
  const int lp = bid >> 3;
  const int m0 = (xcd * 36 + (lp >> 3)) * 128;
  const int n0 = (lp & 7) * 128;
  const int t = threadIdx.x;
  const int lane = t & 63;
  const int wave = t >> 6;
  const int wm = wave >> 1, wn = wave & 1;
  const int r16 = lane & 15;
  const int kq = lane >> 4;
  f32x4 acc[4][4];
  #pragma unroll
  for (int i = 0; i < 4; i++)
    #pragma unroll
    for (int j = 0; j < 4; j++) acc[i][j] = (f32x4){0.f, 0.f, 0.f, 0.f};

  const u16* gA[4]; const u16* gB[4];
  int lofs[4];
  #pragma unroll
  for (int i = 0; i < 4; i++) {
    int seg = i * 256 + t;
    int row = seg >> 3, s = seg & 7;
    int sw = (s ^ (row & 7)) << 3;
    gA[i] = Hh  + (size_t)(m0 + row) * 512 + sw;
    gB[i] = WcT + (size_t)(n0 + row) * 512 + sw;
    lofs[i] = (i * 256 + (t & 192)) << 3;
  }
  #pragma unroll
  for (int i = 0; i < 4; i++) {
    gload16(gA[i], smem + lofs[i]);
    gload16(gB[i], smem + 8192 + lofs[i]);
  }
  __syncthreads();
  int buf = 0;
  for (int it = 0; it < 8; ++it) {
    if (it < 7) {
      int nb = (buf ^ 1) * 16384;
      int k0n = (it + 1) * 64;
      #pragma unroll
      for (int i = 0; i < 4; i++) {
        gload16(gA[i] + k0n, smem + nb + lofs[i]);
        gload16(gB[i] + k0n, smem + nb + 8192 + lofs[i]);
      }
    }
    const u16* Ab = smem + buf * 16384;
    const u16* Bb = Ab + 8192;
    #pragma unroll
    for (int kh = 0; kh < 2; kh++) {
      s16x8 af[4], bfr[4];
      #pragma unroll
      for (int i = 0; i < 4; i++) {
        int r = wm * 64 + i * 16 + r16;
        af[i] = *(const s16x8*)&Ab[r * 64 + (((kq + kh * 4) ^ (r & 7)) << 3)];
      }
      #pragma unroll
      for (int j = 0; j < 4; j++) {
        int r = wn * 64 + j * 16 + r16;
        bfr[j] = *(const s16x8*)&Bb[r * 64 + (((kq + kh * 4) ^ (r & 7)) << 3)];
      }
      #pragma unroll
      for (int i = 0; i < 4; i++)
        #pragma unroll
        for (int j = 0; j < 4; j++)
          acc[i][j] = __builtin_amdgcn_mfma_f32_16x16x32_bf16(af[i], bfr[j], acc[i][j], 0, 0, 0);
    }
    __syncthreads();
    buf ^= 1;
  }

  float* Cs = (float*)smem;   // padded stride 132
  const bool isQ1 = (n0 >= 512);
  #pragma unroll
  for (int c = 0; c < 4; c++) {
    __syncthreads();
    if ((c >> 1) == wm) {
      const int cbase = (c & 1) * 32;
      #pragma unroll
      for (int ii = 0; ii < 2; ii++) {
        const int i = (cbase >> 4) + ii;
        #pragma unroll
        for (int j = 0; j < 4; j++) {
          #pragma unroll
          for (int r = 0; r < 4; r++) {
            int rrow = i * 16 + (lane >> 4) * 4 + r - cbase;
            int ccol = wn * 64 + j * 16 + r16;
            Cs[rrow * 132 + ccol] = acc[i][j][r];
          }
        }
      }
    }
    __syncthreads();
    const int row = t >> 3, cg = (t & 7) * 16;
    const int gm = m0 + c * 32 + row;
    s16x8 o0, o1;
    #pragma unroll
    for (int x = 0; x < 8; x++) o0[x] = (short)f2bf(Cs[row * 132 + cg + x]);
    #pragma unroll
    for (int x = 0; x < 8; x++) o1[x] = (short)f2bf(Cs[row * 132 + cg + 8 + x]);
    u16* dst;
    if (!isQ1) {
      dst = Q0 + (size_t)gm * 512 + (n0 + cg);
    } else {
      int s = gm / 192, o = gm - s * 192;
      dst = Q1T + ((size_t)o * 192 + s) * 512 + (n0 - 512 + cg);
    }
    *(s16x8*)dst = o0;
    *(s16x8*)(dst + 8) = o1;
  }
}

// ================= kmg v2: batched bf16 MFMA, BM=64 BN=64 BK=128 dbuf (4 K-iters) =============
// mode: 0 = plain store, 1 = relu+bias store, 2 = relu+bias column-sum only (-> csum[4][512])
struct MJob { const u16* A; const u16* BT; const float* bias; float* C; float* csum; int Mreal; int mode; };
struct MJobs { MJob j[8]; int cum[9]; int njobs; };

__global__ __launch_bounds__(256) void kmg(MJobs js) {
  int bi = blockIdx.x;
  int ji = 0;
  while (ji + 1 < js.njobs && bi >= js.cum[ji + 1]) ji++;
  MJob job = js.j[ji];
  int local = bi - js.cum[ji];
  int m0 = (local >> 3) * 64, n0 = (local & 7) * 64;

  __shared__ u16 smem[2 * 16384];   // 64 KB: [buf][A 8192 u16 | B 8192 u16]
  const int t = threadIdx.x;
  const int lane = t & 63;
  const int wv = t >> 6;
  const int r16 = lane & 15;
  const int kq = lane >> 4;
  f32x4 acc[4];
  #pragma unroll
  for (int j = 0; j < 4; j++) acc[j] = (f32x4){0.f,0.f,0.f,0.f};

  const u16* gA[4]; const u16* gB[4]; int lofs[4];
  #pragma unroll
  for (int i = 0; i < 4; i++) {
    int seg = i * 256 + t;
    int row = seg >> 4, s = seg & 15;
    int sw = (s ^ (row & 15)) << 3;
    gA[i] = job.A  + (size_t)(m0 + row) * 512 + sw;
    gB[i] = job.BT + (size_t)(n0 + row) * 512 + sw;
    lofs[i] = (i * 256 + (t & 192)) << 3;
  }
  #pragma unroll
  for (int i = 0; i < 4; i++) {
    gload16(gA[i], smem + lofs[i]);
    gload16(gB[i], smem + 8192 + lofs[i]);
  }
  __syncthreads();
  int buf = 0;
  for (int it = 0; it < 4; ++it) {
    if (it < 3) {
      int nb = (buf ^ 1) * 16384;
      int k0n = (it + 1) * 128;
      #pragma unroll
      for (int i = 0; i < 4; i++) {
        gload16(gA[i] + k0n, smem + nb + lofs[i]);
        gload16(gB[i] + k0n, smem + nb + 8192 + lofs[i]);
      }
    }
    const u16* Ab = smem + buf * 16384;
    const u16* Bb = Ab + 8192;
    #pragma unroll
    for (int kh = 0; kh < 4; kh++) {
      int q = kh * 4 + kq;
      int ra = wv * 16 + r16;
      s16x8 af = *(const s16x8*)&Ab[ra * 128 + ((q ^ (ra & 15)) << 3)];
      #pragma unroll
      for (int j = 0; j < 4; j++) {
        int rb = j * 16 + r16;
        s16x8 bfr = *(const s16x8*)&Bb[rb * 128 + ((q ^ (rb & 15)) << 3)];
        acc[j] = __builtin_amdgcn_mfma_f32_16x16x32_bf16(af, bfr, acc[j], 0, 0, 0);
      }
    }
    __syncthreads();
    buf ^= 1;
  }

  float bj[4] = {0.f,0.f,0.f,0.f};
  if (job.mode) {
    #pragma unroll
    for (int j = 0; j < 4; j++) bj[j] = job.bias[n0 + j * 16 + r16];
  }
  if (job.mode == 2) {
    // column-sum of relu(acc+bias) over this block's valid rows
    float fsum[4];
    #pragma unroll
    for (int j = 0; j < 4; j++) {
      fsum[j] = 0.f;
      #pragma unroll
      for (int r = 0; r < 4; r++) {
        int grow = m0 + wv * 16 + kq * 4 + r;
        if (grow < job.Mreal) fsum[j] += fmaxf(acc[j][r] + bj[j], 0.f);
      }
    }
    float (*red)[64] = (float(*)[64])smem;   // 16 x 64 floats (reuse LDS after final barrier)
    int cix = wv * 4 + kq;
    #pragma unroll
    for (int j = 0; j < 4; j++) red[cix][j * 16 + r16] = fsum[j];
    __syncthreads();
    if (t < 64) {
      float s = 0.f;
      #pragma unroll
      for (int c = 0; c < 16; c++) s += red[c][t];
      job.csum[(size_t)(m0 >> 6) * 512 + n0 + t] = s;
    }
    return;
  }
  #pragma unroll
  for (int j = 0; j < 4; j++) {
    int col = n0 + j * 16 + r16;
    #pragma unroll
    for (int r = 0; r < 4; r++) {
      int grow = m0 + wv * 16 + kq * 4 + r;
      if (grow < job.Mreal) {
        float v = acc[j][r] + bj[j];
        if (job.mode == 1) v = fmaxf(v, 0.f);
        job.C[(size_t)grow * 512 + col] = v;
      }
    }
  }
}

// ================= kpassfin: fused streaming pass + per-row finish ("last block finishes") =====
struct PFP {
  const u16 *Q0, *Q1T;
  const float *u0, *v0, *u1, *v1;
  const float *b0b, *b0p, *b1b, *b1p;
  const float *fc4part;                // [4][512]
  const float *fcS, *fcO;
  float *part, *sobj;
  float *tot, *addS, *addO;
  u16 *totb, *aSb, *aOb;
  int *cnt;     // [192] per-row arrival counters (this step's slice)
  int *sflag;   // [1]   sobj-ready flag (this step's slot)
};

__global__ __launch_bounds__(128) void kpassfin(PFP P) {
  const int bid = blockIdx.x;
  const int t = threadIdx.x;
  __shared__ int isLast;

  if (bid < 4) {
    // sobj = colsum partials summed (deterministic fixed order)
    int d = bid * 128 + t;
    P.sobj[d] = P.fc4part[d] + P.fc4part[512 + d] + P.fc4part[1024 + d] + P.fc4part[1536 + d];
    __threadfence();
    __syncthreads();
    if (t == 0) __hip_atomic_fetch_add(P.sflag, 1, __ATOMIC_ACQ_REL, __HIP_MEMORY_SCOPE_AGENT);
    return;
  }

  int tt;
  if (bid < 21) {
    tt = bid + 188;                    // pad rows 192..208
  } else {
    int j = bid - 21;                  // 0..1535
    int so = j >> 3;
    int z = (j >> 2) & 1;
    int chunk = j & 3;
    int d = t * 4;
    const u16* Q = z ? P.Q1T : P.Q0;
    const float* fixtab  = z ? P.v1 : P.u0;
    const float* looptab = z ? P.u1 : P.v0;
    const float* bb = z ? P.b1b : P.b0b;
    f32x4 fix = *(const f32x4*)&fixtab[(size_t)so * 512 + d] + *(const f32x4*)&bb[d];
    f32x4 acc = {0.f,0.f,0.f,0.f};
    const u16* qbase = Q + ((size_t)so * 192 + chunk * 48) * 512 + d;
    const float* lbase = looptab + (size_t)(chunk * 48) * 512 + d;
    #pragma unroll 4
    for (int r = 0; r < 48; ++r) {
      f32x4 qa = bf4(qbase + (size_t)r * 512);
      f32x4 vv = *(const f32x4*)(lbase + (size_t)r * 512);
      f32x4 val = qa + fix + vv;
      acc.x += fmaxf(val.x, 0.f); acc.y += fmaxf(val.y, 0.f);
      acc.z += fmaxf(val.z, 0.f); acc.w += fmaxf(val.w, 0.f);
    }
    *(f32x4*)&P.part[(((size_t)z * 209 + so) * 4 + chunk) * 512 + d] = acc;
    __threadfence();
    __syncthreads();
    if (t == 0) {
      int old = __hip_atomic_fetch_add(&P.cnt[so], 1, __ATOMIC_ACQ_REL, __HIP_MEMORY_SCOPE_AGENT);
      isLast = (old == 7);
    }
    __syncthreads();
    if (!isLast) return;
    tt = so;
  }

  // wait for sobj (colsum blocks bid 0..3)
  if (t == 0) {
    while (__hip_atomic_load(P.sflag, __ATOMIC_ACQUIRE, __HIP_MEMORY_SCOPE_AGENT) < 4)
      __builtin_amdgcn_s_sleep(2);
  }
  __syncthreads();
  __threadfence();

  // ---- finish row tt ----
  int d = t * 4;
  size_t rowoff = (size_t)tt * 512 + d;
  f32x4 u0r = *(const f32x4*)&P.u0[rowoff];
  f32x4 v0r = *(const f32x4*)&P.v0[rowoff];
  f32x4 u1r = *(const f32x4*)&P.u1[rowoff];
  f32x4 v1r = *(const f32x4*)&P.v1[rowoff];
  f32x4 B0B = *(const f32x4*)&P.b0b[d];
  f32x4 B0P = *(const f32x4*)&P.b0p[d];
  f32x4 B1B = *(const f32x4*)&P.b1b[d];
  f32x4 B1P = *(const f32x4*)&P.b1p[d];
  f32x4 srs = {0.f,0.f,0.f,0.f}, sro = {0.f,0.f,0.f,0.f};
  if (tt < 192) {
    #pragma unroll
    for (int c = 0; c < 4; c++) {
      srs += *(const f32x4*)&P.part[(((size_t)0 * 209 + tt) * 4 + c) * 512 + d];
      sro += *(const f32x4*)&P.part[(((size_t)1 * 209 + tt) * 4 + c) * 512 + d];
    }
    for (int o = 192; o < 209; o++) srs += relu4(B0P + u0r + *(const f32x4*)&P.v0[(size_t)o * 512 + d]);
    for (int s = 192; s < 209; s++) sro += relu4(B1P + *(const f32x4*)&P.u1[(size_t)s * 512 + d] + v1r);
    f32x4 qd0 = bf4(P.Q0 + ((size_t)tt * 193) * 512 + d);
    srs -= relu4(qd0 + u0r + v0r + B0B);
    f32x4 qd1 = bf4(P.Q1T + ((size_t)tt * 193) * 512 + d);
    sro -= relu4(qd1 + u1r + v1r + B1B);
  } else {
    for (int o = 0; o < 209; o++) srs += relu4(B0P + u0r + *(const f32x4*)&P.v0[(size_t)o * 512 + d]);
    srs -= relu4(B0P + u0r + v0r);
    for (int s = 0; s < 209; s++) sro += relu4(B1P + *(const f32x4*)&P.u1[(size_t)s * 512 + d] + v1r);
    sro -= relu4(B1P + u1r + v1r);
  }
  const float inv209 = 1.0f / (float)(209.0 + 1e-7);
  const float inv208 = 1.0f / (float)(208.0 + 1e-7);
  const float invrel = 0.5f / (float)(1.0 + 1e-7);
  f32x4 so4 = *(const f32x4*)&P.sobj[d] * inv209;
  srs *= inv208;
  sro *= inv208;
  f32x4 tt4 = *(const f32x4*)&P.tot[rowoff];
  tt4 += (so4 + srs + sro) * (1.0f / 3.0f);
  *(f32x4*)&P.tot[rowoff] = tt4;
  f32x4 aS = *(const f32x4*)&P.addS[rowoff] + *(const f32x4*)&P.fcS[rowoff] * invrel;
  f32x4 aO = *(const f32x4*)&P.addO[rowoff] + *(const f32x4*)&P.fcO[rowoff] * invrel;
  *(f32x4*)&P.addS[rowoff] = aS;
  *(f32x4*)&P.addO[rowoff] = aO;
  *(s16x4*)&P.totb[rowoff] = pack4(tt4);
  *(s16x4*)&P.aSb[rowoff]  = pack4(aS);
  *(s16x4*)&P.aOb[rowoff]  = pack4(aO);
}

// ================= kheads: out[192][9] =================
__global__ __launch_bounds__(256) void kheads(const float* __restrict__ tot,
    const float* __restrict__ w1a, const float* __restrict__ b1a, const float* __restrict__ w2a, const float* __restrict__ b2a,
    const float* __restrict__ w1b, const float* __restrict__ b1bb, const float* __restrict__ w2b, const float* __restrict__ b2b,
    const float* __restrict__ w1c, const float* __restrict__ b1c, const float* __restrict__ w2c, const float* __restrict__ b2c,
    float* __restrict__ out) {
  int row = blockIdx.x;
  int t = threadIdx.x;
  __shared__ float xs[512];
  xs[t] = tot[(size_t)row * 512 + t];
  xs[t + 256] = tot[(size_t)row * 512 + 256 + t];
  __syncthreads();
  const float* W1[3] = {w1a, w1b, w1c};
  const float* B1[3] = {b1a, b1bb, b1c};
  const float* W2[3] = {w2a, w2b, w2c};
  float p[9];
  #pragma unroll
  for (int hd = 0; hd < 3; hd++) {
    float a = B1[hd][t];
    for (int k = 0; k < 512; k += 4) {
      f32x4 x4 = *(const f32x4*)&xs[k];
      a = fmaf(x4.x, W1[hd][(size_t)(k + 0) * 256 + t], a);
      a = fmaf(x4.y, W1[hd][(size_t)(k + 1) * 256 + t], a);
      a = fmaf(x4.z, W1[hd][(size_t)(k + 2) * 256 + t], a);
      a = fmaf(x4.w, W1[hd][(size_t)(k + 3) * 256 + t], a);
    }
    float h = a > 0.f ? a : 0.2f * a;
    p[hd * 3 + 0] = h * W2[hd][t * 3 + 0];
    p[hd * 3 + 1] = h * W2[hd][t * 3 + 1];
    p[hd * 3 + 2] = h * W2[hd][t * 3 + 2];
  }
  __shared__ float red[9][256];
  #pragma unroll
  for (int c = 0; c < 9; c++) red[c][t] = p[c];
  __syncthreads();
  for (int s = 128; s > 0; s >>= 1) {
    if (t < s) {
      #pragma unroll
      for (int c = 0; c < 9; c++) red[c][t] += red[c][t + s];
    }
    __syncthreads();
  }
  if (t < 9) {
    const float* B2[3] = {b2a, b2b, b2c};
    out[(size_t)row * 9 + t] = red[t][0] + B2[t / 3][t % 3];
  }
}

extern "C" void kernel_launch(void* const* d_in, const int* in_sizes, int n_in,
                              void* d_out, int out_size, void* d_ws, size_t ws_size,
                              hipStream_t stream) {
  const float* xo  = (const float*)d_in[0];
  const float* xw  = (const float*)d_in[1];
  const float* xf  = (const float*)d_in[2];
  const float* xr  = (const float*)d_in[3];
  const float* ow1 = (const float*)d_in[4];
  const float* ob1 = (const float*)d_in[5];
  const float* ow2 = (const float*)d_in[6];
  const float* ob2 = (const float*)d_in[7];
  const float* ww1 = (const float*)d_in[8];
  const float* wb1 = (const float*)d_in[9];
  const float* ww2 = (const float*)d_in[10];
  const float* wb2 = (const float*)d_in[11];
  const float* fw1 = (const float*)d_in[12];
  const float* fb1 = (const float*)d_in[13];
  const float* fw2 = (const float*)d_in[14];
  const float* fb2 = (const float*)d_in[15];
  const float* rw1 = (const float*)d_in[16];
  const float* rb1 = (const float*)d_in[17];
  const float* rw2 = (const float*)d_in[18];
  const float* rb2 = (const float*)d_in[19];
  const float* cw  = (const float*)d_in[20];
  const float* cb  = (const float*)d_in[21];
  const float* tw1 = (const float*)d_in[22];
  const float* tb1 = (const float*)d_in[23];
  const float* tw2 = (const float*)d_in[24];
  const float* tb2 = (const float*)d_in[25];
  const float* ew1 = (const float*)d_in[26];
  const float* eb1 = (const float*)d_in[27];
  const float* ew2 = (const float*)d_in[28];
  const float* eb2 = (const float*)d_in[29];
  const float* sw1 = (const float*)d_in[30];
  const float* sb1 = (const float*)d_in[31];
  const float* sw2 = (const float*)d_in[32];
  const float* sb2 = (const float*)d_in[33];
  float* out = (float*)d_out;

  char* p = (char*)d_ws;
  auto alloc = [&](size_t bytes) { char* r = p; p += (bytes + 255) & ~(size_t)255; return r; };
  const size_t SZ = 209 * 512 * sizeof(float);   // multiple of 256
  const size_t BSZ = 256 * 512 * sizeof(u16);    // multiple of 256
  float* tot  = (float*)alloc(SZ);
  // --- contiguous zero block: addS, addO, totb, aSb, aOb, sync ---
  float* addS = (float*)alloc(SZ);
  float* addO = (float*)alloc(SZ);
  u16*   totb = (u16*)alloc(BSZ);
  u16*   aSb  = (u16*)alloc(BSZ);
  u16*   aOb  = (u16*)alloc(BSZ);
  int*   sync = (int*)alloc(4096);               // cnt[4][192] + sflag[4]
  // ---------------------------------------------------------------
  float* fc4part = (float*)alloc(4 * 512 * sizeof(float));
  float* fcS  = (float*)alloc(SZ);
  float* fcO  = (float*)alloc(SZ);
  float* u0   = (float*)alloc(SZ);
  float* v0   = (float*)alloc(SZ);
  float* u1   = (float*)alloc(SZ);
  float* v1   = (float*)alloc(SZ);
  float* hid  = (float*)alloc(SZ);
  float* sobj = (float*)alloc(512 * sizeof(float));
  float* part = (float*)alloc((size_t)2 * 209 * 4 * 512 * sizeof(float));
  float* b0b  = (float*)alloc(512 * sizeof(float));
  float* b0p  = (float*)alloc(512 * sizeof(float));
  float* b1b  = (float*)alloc(512 * sizeof(float));
  float* b1p  = (float*)alloc(512 * sizeof(float));
  u16* rw2b = (u16*)alloc((size_t)DD * sizeof(u16));
  u16* cwT  = (u16*)alloc((size_t)5 * DD * sizeof(u16));
  u16* Hh  = (u16*)alloc((size_t)36864 * 512 * sizeof(u16));
  u16* WcT = (u16*)alloc((size_t)1024 * 512 * sizeof(u16));
  u16* Q0  = (u16*)alloc((size_t)36864 * 512 * sizeof(u16));
  u16* Q1T = (u16*)alloc((size_t)36864 * 512 * sizeof(u16));

  // zero addS, addO, totb, aSb, aOb, sync in one shot (contiguous)
  hipMemsetAsync(addS, 0, 2 * SZ + 3 * BSZ + 4096, stream);

  PrepP pp;
  pp.xo = xo; pp.xw = xw; pp.xf = xf;
  pp.ow1 = ow1; pp.ob1 = ob1; pp.ww1 = ww1; pp.wb1 = wb1; pp.fw1 = fw1; pp.fb1 = fb1;
  pp.hid = hid;
  pp.rw2 = rw2; pp.rw2b = rw2b;
  pp.cw = cw; pp.cwT = cwT;
  pp.cb = cb; pp.rb2 = rb2;
  pp.b0b = b0b; pp.b0p = b0p; pp.b1b = b1b; pp.b1p = b1p;
  pp.xr = xr; pp.rw1 = rw1; pp.rb1 = rb1; pp.Hh = Hh;
  kprep<<<10841, 256, 0, stream>>>(pp);

  MidP mp{};
  mp.sj.j[0] = { hid,             ow2, ob2, tot,             totb,             192, 0 };
  mp.sj.j[1] = { hid + 192 * 512, ww2, wb2, tot + 192 * 512, totb + 192 * 512,  16, 0 };
  mp.sj.j[2] = { hid + 208 * 512, fw2, fb2, tot + 208 * 512, totb + 208 * 512,   1, 0 };
  mp.sj.njobs = 3;
  mp.sj.cum[0] = 0;
  for (int i = 0; i < 3; i++) mp.sj.cum[i + 1] = mp.sj.cum[i] + ((mp.sj.j[i].M + 31) / 32) * 8;
  mp.mj[0] = { rw2b, cwT,      WcT };
  mp.mj[1] = { rw2b, cwT + DD, WcT + DD };
  kmid<<<128, 256, 0, stream>>>(mp);

  kbig<<<2304, 256, 0, stream>>>(Hh, WcT, Q0, Q1T);

  MJobs st{};
  st.j[0] = { totb, cwT + 4 * DD, cb + 4 * 512, nullptr, fc4part, 209, 2 };
  st.j[1] = { totb, cwT + 2 * DD, cb + 2 * 512, fcS, nullptr, 209, 1 };
  st.j[2] = { totb, cwT + 3 * DD, cb + 3 * 512, fcO, nullptr, 209, 1 };
  st.j[3] = { aSb,  cwT,          nullptr,      u0,  nullptr, 209, 0 };
  st.j[4] = { aOb,  cwT,          nullptr,      v0,  nullptr, 209, 0 };
  st.j[5] = { aSb,  cwT + DD,     nullptr,      u1,  nullptr, 209, 0 };
  st.j[6] = { aOb,  cwT + DD,     nullptr,      v1,  nullptr, 209, 0 };
  st.njobs = 7;
  st.cum[0] = 0;
  for (int i = 0; i < 7; i++) st.cum[i + 1] = st.cum[i] + 4 * 8;  // 4 mtiles * 8 ntiles

  for (int step = 0; step < 4; step++) {
    kmg<<<st.cum[7], 256, 0, stream>>>(st);
    PFP pf;
    pf.Q0 = Q0; pf.Q1T = Q1T;
    pf.u0 = u0; pf.v0 = v0; pf.u1 = u1; pf.v1 = v1;
    pf.b0b = b0b; pf.b0p = b0p; pf.b1b = b1b; pf.b1p = b1p;
    pf.fc4part = fc4part;
    pf.fcS = fcS; pf.fcO = fcO;
    pf.part = part; pf.sobj = sobj;
    pf.tot = tot; pf.addS = addS; pf.addO = addO;
    pf.totb = totb; pf.aSb = aSb; pf.aOb = aOb;
    pf.cnt = sync + step * 192;
    pf.sflag = sync + 768 + step;
    kpassfin<<<1557, 128, 0, stream>>>(pf);
  }

  kheads<<<192, 256, 0, stream>>>(tot, tw1, tb1, tw2, tb2, ew1, eb1, ew2, eb2, sw1, sb1, sw2, sb2, out);
}

// Round 9
// 399.382 us; speedup vs baseline: 2.0916x; 2.0916x over previous
//
#include <hip/hip_runtime.h>
#include <stdint.h>

typedef unsigned short u16;
typedef __attribute__((ext_vector_type(4))) float f32x4;
typedef __attribute__((ext_vector_type(8))) short s16x8;
typedef __attribute__((ext_vector_type(4))) short s16x4;

#define DD (512*512)

__device__ inline u16 f2bf(float f) {
  uint32_t u = __float_as_uint(f);
  u = (u + 0x7FFFu + ((u >> 16) & 1u)) >> 16;
  return (u16)u;
}
__device__ inline float bflo(uint32_t w) { return __uint_as_float(w << 16); }
__device__ inline float bfhi(uint32_t w) { return __uint_as_float(w & 0xFFFF0000u); }
__device__ inline f32x4 relu4(f32x4 v) {
  f32x4 r;
  r.x = fmaxf(v.x, 0.f); r.y = fmaxf(v.y, 0.f);
  r.z = fmaxf(v.z, 0.f); r.w = fmaxf(v.w, 0.f);
  return r;
}
__device__ inline f32x4 bf4(const u16* p) {
  uint2 w = *(const uint2*)p;
  f32x4 r; r.x = bflo(w.x); r.y = bfhi(w.x); r.z = bflo(w.y); r.w = bfhi(w.y);
  return r;
}
__device__ inline s16x4 pack4(f32x4 v) {
  s16x4 o;
  o[0] = (short)f2bf(v.x); o[1] = (short)f2bf(v.y);
  o[2] = (short)f2bf(v.z); o[3] = (short)f2bf(v.w);
  return o;
}
__device__ inline void gload16(const void* g, void* l) {
  __builtin_amdgcn_global_load_lds(
      (const __attribute__((address_space(1))) void*)g,
      (__attribute__((address_space(3))) void*)l, 16, 0, 0);
}

// ================= kprep: ktotl1 + kcast(rw2) + kwcast(cw) + kmisc + kH fused =================
struct PrepP {
  const float *xo, *xw, *xf;
  const float *ow1, *ob1, *ww1, *wb1, *fw1, *fb1;
  float* hid;
  const float* rw2; u16* rw2b;
  const float* cw; u16* cwT;
  const float* cb; const float* rb2;
  float *b0b, *b0p, *b1b, *b1p;
  const float *xr, *rw1, *rb1; u16* Hh;
};

__global__ __launch_bounds__(256) void kprep(PrepP pp) {
  __shared__ __align__(16) float plds[1088];
  const int bid = blockIdx.x;
  const int t = threadIdx.x;
  if (bid < 209) {
    int tc = bid;
    const float* x; const float* w; const float* b; int K;
    if (tc < 192)      { x = pp.xo + tc * 42;         w = pp.ow1; b = pp.ob1; K = 42; }
    else if (tc < 208) { x = pp.xw + (tc - 192) * 15; w = pp.ww1; b = pp.wb1; K = 15; }
    else               { x = pp.xf;                   w = pp.fw1; b = pp.fb1; K = 16; }
    float* xs = plds;
    if (t < K) xs[t] = x[t];
    __syncthreads();
    #pragma unroll
    for (int dd = 0; dd < 2; dd++) {
      int d = t + dd * 256;
      float acc = b[d];
      for (int k = 0; k < K; k++) acc = fmaf(xs[k], w[k * 512 + d], acc);
      pp.hid[(size_t)tc * 512 + d] = fmaxf(acc, 0.f);
    }
  } else if (bid < 337) {
    int g = (bid - 209) * 256 + t;
    f32x4 a = *(const f32x4*)&pp.rw2[(size_t)g * 8];
    f32x4 b = *(const f32x4*)&pp.rw2[(size_t)g * 8 + 4];
    s16x8 o;
    o[0] = (short)f2bf(a.x); o[1] = (short)f2bf(a.y); o[2] = (short)f2bf(a.z); o[3] = (short)f2bf(a.w);
    o[4] = (short)f2bf(b.x); o[5] = (short)f2bf(b.y); o[6] = (short)f2bf(b.z); o[7] = (short)f2bf(b.w);
    *(s16x8*)&pp.rw2b[(size_t)g * 8] = o;
  } else if (bid < 1617) {
    int local = bid - 337;
    int bx = local & 15, by = (local >> 4) & 15, bz = local >> 8;
    float (*tile)[33] = (float(*)[33])plds;
    const float* src = pp.cw + (size_t)bz * DD;
    int k0 = bx * 32, n0 = by * 32;
    #pragma unroll
    for (int i = 0; i < 4; i++) {
      int idx = t + i * 256; int r = idx >> 5, c = idx & 31;
      tile[r][c] = src[(size_t)(k0 + r) * 512 + n0 + c];
    }
    __syncthreads();
    #pragma unroll
    for (int i = 0; i < 4; i++) {
      int idx = t + i * 256; int r = idx >> 5, c = idx & 31;
      pp.cwT[((size_t)bz * 512 + n0 + r) * 512 + k0 + c] = f2bf(tile[c][r]);
    }
  } else if (bid < 1625) {
    int bx = bid - 1617;
    int dl = t & 63;
    int d = bx * 64 + dl;
    int kg = t >> 6;
    const float* W0 = pp.cw;
    const float* W1 = pp.cw + DD;
    float a0 = 0, p0 = 0, a1 = 0, p1 = 0;
    for (int k = kg * 128; k < (kg + 1) * 128; ++k) {
      float w0 = W0[(size_t)k * 512 + d], w1 = W1[(size_t)k * 512 + d], r = pp.rb2[k];
      a0 = fmaf(r, w0, a0); p0 += w0;
      a1 = fmaf(r, w1, a1); p1 += w1;
    }
    float (*red)[4][64] = (float(*)[4][64])plds;
    red[0][kg][dl] = a0; red[1][kg][dl] = p0; red[2][kg][dl] = a1; red[3][kg][dl] = p1;
    __syncthreads();
    if (kg == 0) {
      float s0  = red[0][0][dl] + red[0][1][dl] + red[0][2][dl] + red[0][3][dl];
      float sp0 = red[1][0][dl] + red[1][1][dl] + red[1][2][dl] + red[1][3][dl];
      float s1  = red[2][0][dl] + red[2][1][dl] + red[2][2][dl] + red[2][3][dl];
      float sp1 = red[3][0][dl] + red[3][1][dl] + red[3][2][dl] + red[3][3][dl];
      float bb0 = pp.cb[0 * 512 + d], bb1 = pp.cb[1 * 512 + d];
      pp.b0b[d] = s0 + bb0;
      pp.b0p[d] = 0.001f * sp0 + bb0;
      pp.b1b[d] = s1 + bb1;
      pp.b1p[d] = 0.001f * sp1 + bb1;
    }
  } else {
    int gid = (bid - 1625) * 256 + t;
    int m = gid >> 6;
    int dg = (gid & 63) * 8;
    float x0 = pp.xr[m * 2], x1 = pp.xr[m * 2 + 1];
    s16x8 o;
    #pragma unroll
    for (int j = 0; j < 8; j++) {
      int dd = dg + j;
      float v = fmaf(x0, pp.rw1[dd], fmaf(x1, pp.rw1[512 + dd], pp.rb1[dd]));
      o[j] = (short)f2bf(fmaxf(v, 0.f));
    }
    *(s16x8*)&pp.Hh[(size_t)m * 512 + dg] = o;
  }
}

// ================= kmid: ksmall-pre (fp32 tot layer2) + kmg-pre (rw2b @ cwT -> WcT^T) fused ====
struct SJob { const float* A; const float* B; const float* bias; float* C; u16* Cb; int M; int act; };
struct SJobs { SJob j[4]; int cum[5]; int njobs; };
struct PMJob { const u16* A; const u16* BT; u16* W; };   // W: bf16 [n][k] transposed dest
struct MidP { SJobs sj; PMJob mj[2]; };

__global__ __launch_bounds__(256) void kmid(MidP mp) {
  __shared__ __align__(16) u16 mlds[24576];   // 48 KB
  const int t = threadIdx.x;
  if (blockIdx.x < 64) {
    // ---------- ksmall fp32 GEMM ----------
    int bi = blockIdx.x;
    int ji = 0;
    while (ji + 1 < mp.sj.njobs && bi >= mp.sj.cum[ji + 1]) ji++;
    SJob job = mp.sj.j[ji];
    int local = bi - mp.sj.cum[ji];
    int mt = local >> 3, nt = local & 7;
    int m0 = mt * 32, n0 = nt * 64;
    float* As = (float*)mlds;
    float* Bs = As + 32 * 36;
    int row = t >> 3;
    int cg  = (t & 7) * 8;
    f32x4 accA = {0.f,0.f,0.f,0.f}, accB = {0.f,0.f,0.f,0.f};
    for (int k0 = 0; k0 < 512; k0 += 32) {
      __syncthreads();
      {
        int ar = t >> 3, ac = (t & 7) * 4;
        f32x4 av = {0.f,0.f,0.f,0.f};
        if (m0 + ar < job.M) av = *(const f32x4*)&job.A[(size_t)(m0 + ar) * 512 + k0 + ac];
        *(f32x4*)&As[ar * 36 + ac] = av;
      }
      #pragma unroll
      for (int i = 0; i < 2; i++) {
        int idx = t + i * 256;
        int bk = idx >> 4, bn = (idx & 15) * 4;
        *(f32x4*)&Bs[bk * 64 + bn] = *(const f32x4*)&job.B[(size_t)(k0 + bk) * 512 + n0 + bn];
      }
      __syncthreads();
      #pragma unroll
      for (int kk = 0; kk < 32; kk += 4) {
        f32x4 a4 = *(const f32x4*)&As[row * 36 + kk];
        #pragma unroll
        for (int q = 0; q < 4; q++) {
          f32x4 b0 = *(const f32x4*)&Bs[(kk + q) * 64 + cg];
          f32x4 b1 = *(const f32x4*)&Bs[(kk + q) * 64 + cg + 4];
          float av = a4[q];
          accA += av * b0;
          accB += av * b1;
        }
      }
    }
    int r = m0 + row;
    if (r < job.M) {
      f32x4 b0 = {0.f,0.f,0.f,0.f}, b1 = {0.f,0.f,0.f,0.f};
      if (job.bias) { b0 = *(const f32x4*)&job.bias[n0 + cg]; b1 = *(const f32x4*)&job.bias[n0 + cg + 4]; }
      f32x4 o0 = accA + b0, o1 = accB + b1;
      if (job.act) { o0 = relu4(o0); o1 = relu4(o1); }
      *(f32x4*)&job.C[(size_t)r * 512 + n0 + cg]     = o0;
      *(f32x4*)&job.C[(size_t)r * 512 + n0 + cg + 4] = o1;
      if (job.Cb) {
        s16x8 ob;
        ob[0] = (short)f2bf(o0.x); ob[1] = (short)f2bf(o0.y);
        ob[2] = (short)f2bf(o0.z); ob[3] = (short)f2bf(o0.w);
        ob[4] = (short)f2bf(o1.x); ob[5] = (short)f2bf(o1.y);
        ob[6] = (short)f2bf(o1.z); ob[7] = (short)f2bf(o1.w);
        *(s16x8*)&job.Cb[(size_t)r * 512 + n0 + cg] = ob;
      }
    }
  } else {
    // ---------- kmg-pre: 512x512x512 bf16 MFMA, BM=64 BN=128 BK=64 dbuf; writes WcT transposed ----
    int bi = blockIdx.x - 64;
    int ji = bi >> 5;
    int local = bi & 31;
    PMJob job = mp.mj[ji];
    int m0 = (local >> 2) * 64, n0 = (local & 3) * 128;
    u16* smem = mlds;
    const int lane = t & 63;
    const int wave = t >> 6;
    const int wm = wave >> 1, wn = wave & 1;
    const int r16 = lane & 15;
    const int kq = lane >> 4;
    f32x4 acc[2][4];
    #pragma unroll
    for (int i = 0; i < 2; i++)
      #pragma unroll
      for (int j = 0; j < 4; j++) acc[i][j] = (f32x4){0.f,0.f,0.f,0.f};
    const u16* gA[2]; int laofs[2];
    const u16* gB[4]; int lbofs[4];
    #pragma unroll
    for (int i = 0; i < 2; i++) {
      int seg = i * 256 + t;
      int row = seg >> 3, s = seg & 7;
      gA[i] = job.A + (size_t)(m0 + row) * 512 + ((s ^ (row & 7)) << 3);
      laofs[i] = (i * 256 + (t & 192)) << 3;
    }
    #pragma unroll
    for (int i = 0; i < 4; i++) {
      int seg = i * 256 + t;
      int row = seg >> 3, s = seg & 7;
      gB[i] = job.BT + (size_t)(n0 + row) * 512 + ((s ^ (row & 7)) << 3);
      lbofs[i] = 4096 + ((i * 256 + (t & 192)) << 3);
    }
    #pragma unroll
    for (int i = 0; i < 2; i++) gload16(gA[i], smem + laofs[i]);
    #pragma unroll
    for (int i = 0; i < 4; i++) gload16(gB[i], smem + lbofs[i]);
    __syncthreads();
    int buf = 0;
    for (int it = 0; it < 8; ++it) {
      if (it < 7) {
        int nb = (buf ^ 1) * 12288;
        int k0n = (it + 1) * 64;
        #pragma unroll
        for (int i = 0; i < 2; i++) gload16(gA[i] + k0n, smem + nb + laofs[i]);
        #pragma unroll
        for (int i = 0; i < 4; i++) gload16(gB[i] + k0n, smem + nb + lbofs[i]);
      }
      const u16* Ab = smem + buf * 12288;
      const u16* Bb = Ab + 4096;
      #pragma unroll
      for (int kh = 0; kh < 2; kh++) {
        s16x8 af[2], bfr[4];
        #pragma unroll
        for (int i = 0; i < 2; i++) {
          int r = wm * 32 + i * 16 + r16;
          af[i] = *(const s16x8*)&Ab[r * 64 + (((kq + kh * 4) ^ (r & 7)) << 3)];
        }
        #pragma unroll
        for (int j = 0; j < 4; j++) {
          int r = wn * 64 + j * 16 + r16;
          bfr[j] = *(const s16x8*)&Bb[r * 64 + (((kq + kh * 4) ^ (r & 7)) << 3)];
        }
        #pragma unroll
        for (int i = 0; i < 2; i++)
          #pragma unroll
          for (int j = 0; j < 4; j++)
            acc[i][j] = __builtin_amdgcn_mfma_f32_16x16x32_bf16(af[i], bfr[j], acc[i][j], 0, 0, 0);
      }
      __syncthreads();
      buf ^= 1;
    }
    // epilogue: write transposed bf16 directly into WcT slab: W[col][k]
    #pragma unroll
    for (int i = 0; i < 2; i++) {
      int rbase = m0 + wm * 32 + i * 16 + kq * 4;   // k index base
      #pragma unroll
      for (int j = 0; j < 4; j++) {
        int col = n0 + wn * 64 + j * 16 + r16;      // n index
        s16x4 o;
        #pragma unroll
        for (int r = 0; r < 4; r++) o[r] = (short)f2bf(acc[i][j][r]);
        *(s16x4*)&job.W[(size_t)col * 512 + rbase] = o;
      }
    }
  }
}

// ================= kbig: Q = H(36864x512) @ WcT^T -> Q0/Q1T, XCD-aware mapping =================
__global__ __launch_bounds__(256) void kbig(const u16* __restrict__ Hh, const u16* __restrict__ WcT,
                                            u16* __restrict__ Q0, u16* __restrict__ Q1T) {
  __shared__ u16 smem[2 * 16384];   // 64 KB dbuf
  const int bid = blockIdx.x;
  const int xcd = bid & 7;
  const int lp = bid >> 3;
  const int m0 = (xcd * 36 + (lp >> 3)) * 128;
  const int n0 = (lp & 7) * 128;
  const int t = threadIdx.x;
  const int lane = t & 63;
  const int wave = t >> 6;
  const int wm = wave >> 1, wn = wave & 1;
  const int r16 = lane & 15;
  const int kq = lane >> 4;
  f32x4 acc[4][4];
  #pragma unroll
  for (int i = 0; i < 4; i++)
    #pragma unroll
    for (int j = 0; j < 4; j++) acc[i][j] = (f32x4){0.f, 0.f, 0.f, 0.f};

  const u16* gA[4]; const u16* gB[4];
  int lofs[4];
  #pragma unroll
  for (int i = 0; i < 4; i++) {
    int seg = i * 256 + t;
    int row = seg >> 3, s = seg & 7;
    int sw = (s ^ (row & 7)) << 3;
    gA[i] = Hh  + (size_t)(m0 + row) * 512 + sw;
    gB[i] = WcT + (size_t)(n0 + row) * 512 + sw;
    lofs[i] = (i * 256 + (t & 192)) << 3;
  }
  #pragma unroll
  for (int i = 0; i < 4; i++) {
    gload16(gA[i], smem + lofs[i]);
    gload16(gB[i], smem + 8192 + lofs[i]);
  }
  __syncthreads();
  int buf = 0;
  for (int it = 0; it < 8; ++it) {
    if (it < 7) {
      int nb = (buf ^ 1) * 16384;
      int k0n = (it + 1) * 64;
      #pragma unroll
      for (int i = 0; i < 4; i++) {
        gload16(gA[i] + k0n, smem + nb + lofs[i]);
        gload16(gB[i] + k0n, smem + nb + 8192 + lofs[i]);
      }
    }
    const u16* Ab = smem + buf * 16384;
    const u16* Bb = Ab + 8192;
    #pragma unroll
    for (int kh = 0; kh < 2; kh++) {
      s16x8 af[4], bfr[4];
      #pragma unroll
      for (int i = 0; i < 4; i++) {
        int r = wm * 64 + i * 16 + r16;
        af[i] = *(const s16x8*)&Ab[r * 64 + (((kq + kh * 4) ^ (r & 7)) << 3)];
      }
      #pragma unroll
      for (int j = 0; j < 4; j++) {
        int r = wn * 64 + j * 16 + r16;
        bfr[j] = *(const s16x8*)&Bb[r * 64 + (((kq + kh * 4) ^ (r & 7)) << 3)];
      }
      #pragma unroll
      for (int i = 0; i < 4; i++)
        #pragma unroll
        for (int j = 0; j < 4; j++)
          acc[i][j] = __builtin_amdgcn_mfma_f32_16x16x32_bf16(af[i], bfr[j], acc[i][j], 0, 0, 0);
    }
    __syncthreads();
    buf ^= 1;
  }

  float* Cs = (float*)smem;   // padded stride 132
  const bool isQ1 = (n0 >= 512);
  #pragma unroll
  for (int c = 0; c < 4; c++) {
    __syncthreads();
    if ((c >> 1) == wm) {
      const int cbase = (c & 1) * 32;
      #pragma unroll
      for (int ii = 0; ii < 2; ii++) {
        const int i = (cbase >> 4) + ii;
        #pragma unroll
        for (int j = 0; j < 4; j++) {
          #pragma unroll
          for (int r = 0; r < 4; r++) {
            int rrow = i * 16 + (lane >> 4) * 4 + r - cbase;
            int ccol = wn * 64 + j * 16 + r16;
            Cs[rrow * 132 + ccol] = acc[i][j][r];
          }
        }
      }
    }
    __syncthreads();
    const int row = t >> 3, cg = (t & 7) * 16;
    const int gm = m0 + c * 32 + row;
    s16x8 o0, o1;
    #pragma unroll
    for (int x = 0; x < 8; x++) o0[x] = (short)f2bf(Cs[row * 132 + cg + x]);
    #pragma unroll
    for (int x = 0; x < 8; x++) o1[x] = (short)f2bf(Cs[row * 132 + cg + 8 + x]);
    u16* dst;
    if (!isQ1) {
      dst = Q0 + (size_t)gm * 512 + (n0 + cg);
    } else {
      int s = gm / 192, o = gm - s * 192;
      dst = Q1T + ((size_t)o * 192 + s) * 512 + (n0 - 512 + cg);
    }
    *(s16x8*)dst = o0;
    *(s16x8*)(dst + 8) = o1;
  }
}

// ================= kmg v2: batched bf16 MFMA, BM=64 BN=64 BK=128 dbuf (4 K-iters) =============
// mode: 0 = plain store, 1 = relu+bias store, 2 = relu+bias column-sum only (-> csum[4][512])
struct MJob { const u16* A; const u16* BT; const float* bias; float* C; float* csum; int Mreal; int mode; };
struct MJobs { MJob j[8]; int cum[9]; int njobs; };

__global__ __launch_bounds__(256) void kmg(MJobs js) {
  int bi = blockIdx.x;
  int ji = 0;
  while (ji + 1 < js.njobs && bi >= js.cum[ji + 1]) ji++;
  MJob job = js.j[ji];
  int local = bi - js.cum[ji];
  int m0 = (local >> 3) * 64, n0 = (local & 7) * 64;

  __shared__ u16 smem[2 * 16384];   // 64 KB: [buf][A 8192 u16 | B 8192 u16]
  const int t = threadIdx.x;
  const int lane = t & 63;
  const int wv = t >> 6;
  const int r16 = lane & 15;
  const int kq = lane >> 4;
  f32x4 acc[4];
  #pragma unroll
  for (int j = 0; j < 4; j++) acc[j] = (f32x4){0.f,0.f,0.f,0.f};

  const u16* gA[4]; const u16* gB[4]; int lofs[4];
  #pragma unroll
  for (int i = 0; i < 4; i++) {
    int seg = i * 256 + t;
    int row = seg >> 4, s = seg & 15;
    int sw = (s ^ (row & 15)) << 3;
    gA[i] = job.A  + (size_t)(m0 + row) * 512 + sw;
    gB[i] = job.BT + (size_t)(n0 + row) * 512 + sw;
    lofs[i] = (i * 256 + (t & 192)) << 3;
  }
  #pragma unroll
  for (int i = 0; i < 4; i++) {
    gload16(gA[i], smem + lofs[i]);
    gload16(gB[i], smem + 8192 + lofs[i]);
  }
  __syncthreads();
  int buf = 0;
  for (int it = 0; it < 4; ++it) {
    if (it < 3) {
      int nb = (buf ^ 1) * 16384;
      int k0n = (it + 1) * 128;
      #pragma unroll
      for (int i = 0; i < 4; i++) {
        gload16(gA[i] + k0n, smem + nb + lofs[i]);
        gload16(gB[i] + k0n, smem + nb + 8192 + lofs[i]);
      }
    }
    const u16* Ab = smem + buf * 16384;
    const u16* Bb = Ab + 8192;
    #pragma unroll
    for (int kh = 0; kh < 4; kh++) {
      int q = kh * 4 + kq;
      int ra = wv * 16 + r16;
      s16x8 af = *(const s16x8*)&Ab[ra * 128 + ((q ^ (ra & 15)) << 3)];
      #pragma unroll
      for (int j = 0; j < 4; j++) {
        int rb = j * 16 + r16;
        s16x8 bfr = *(const s16x8*)&Bb[rb * 128 + ((q ^ (rb & 15)) << 3)];
        acc[j] = __builtin_amdgcn_mfma_f32_16x16x32_bf16(af, bfr, acc[j], 0, 0, 0);
      }
    }
    __syncthreads();
    buf ^= 1;
  }

  float bj[4] = {0.f,0.f,0.f,0.f};
  if (job.mode) {
    #pragma unroll
    for (int j = 0; j < 4; j++) bj[j] = job.bias[n0 + j * 16 + r16];
  }
  if (job.mode == 2) {
    // column-sum of relu(acc+bias) over this block's valid rows
    float fsum[4];
    #pragma unroll
    for (int j = 0; j < 4; j++) {
      fsum[j] = 0.f;
      #pragma unroll
      for (int r = 0; r < 4; r++) {
        int grow = m0 + wv * 16 + kq * 4 + r;
        if (grow < job.Mreal) fsum[j] += fmaxf(acc[j][r] + bj[j], 0.f);
      }
    }
    float (*red)[64] = (float(*)[64])smem;   // 16 x 64 floats (reuse LDS after final barrier)
    int cix = wv * 4 + kq;
    #pragma unroll
    for (int j = 0; j < 4; j++) red[cix][j * 16 + r16] = fsum[j];
    __syncthreads();
    if (t < 64) {
      float s = 0.f;
      #pragma unroll
      for (int c = 0; c < 16; c++) s += red[c][t];
      job.csum[(size_t)(m0 >> 6) * 512 + n0 + t] = s;
    }
    return;
  }
  #pragma unroll
  for (int j = 0; j < 4; j++) {
    int col = n0 + j * 16 + r16;
    #pragma unroll
    for (int r = 0; r < 4; r++) {
      int grow = m0 + wv * 16 + kq * 4 + r;
      if (grow < job.Mreal) {
        float v = acc[j][r] + bj[j];
        if (job.mode == 1) v = fmaxf(v, 0.f);
        job.C[(size_t)grow * 512 + col] = v;
      }
    }
  }
}

// ================= kpass: per-step streaming pass over Q0/Q1T + sobj from fc4part =============
__global__ __launch_bounds__(128) void kpass(const u16* __restrict__ Q0, const u16* __restrict__ Q1T,
                                             const float* __restrict__ u0, const float* __restrict__ v0,
                                             const float* __restrict__ u1, const float* __restrict__ v1,
                                             const float* __restrict__ b0b, const float* __restrict__ b1b,
                                             const float* __restrict__ fc4part,
                                             float* __restrict__ part, float* __restrict__ sobj) {
  int z = blockIdx.z;
  int t = threadIdx.x;
  if (z == 2) {
    if (blockIdx.y != 0 || blockIdx.x >= 4) return;
    int d = blockIdx.x * 128 + t;
    sobj[d] = fc4part[d] + fc4part[512 + d] + fc4part[1024 + d] + fc4part[1536 + d];
    return;
  }
  int so = blockIdx.x;
  if (so >= 192) return;
  int chunk = blockIdx.y;
  int d = t * 4;
  const u16* Q = z ? Q1T : Q0;
  const float* fixtab  = z ? v1 : u0;
  const float* looptab = z ? u1 : v0;
  const float* bb = z ? b1b : b0b;
  f32x4 fix = *(const f32x4*)&fixtab[(size_t)so * 512 + d] + *(const f32x4*)&bb[d];
  f32x4 acc = {0.f,0.f,0.f,0.f};
  const u16* qbase = Q + ((size_t)so * 192 + chunk * 48) * 512 + d;
  const float* lbase = looptab + (size_t)(chunk * 48) * 512 + d;
  #pragma unroll 4
  for (int r = 0; r < 48; ++r) {
    f32x4 qa = bf4(qbase + (size_t)r * 512);
    f32x4 vv = *(const f32x4*)(lbase + (size_t)r * 512);
    f32x4 val = qa + fix + vv;
    acc.x += fmaxf(val.x, 0.f); acc.y += fmaxf(val.y, 0.f);
    acc.z += fmaxf(val.z, 0.f); acc.w += fmaxf(val.w, 0.f);
  }
  *(f32x4*)&part[(((size_t)z * 209 + so) * 4 + chunk) * 512 + d] = acc;
}

// ================= kfinish: per-step pads, diag, division, tot/addS/addO update =================
__global__ __launch_bounds__(128) void kfinish(const u16* __restrict__ Q0, const u16* __restrict__ Q1T,
                                               const float* __restrict__ u0, const float* __restrict__ v0,
                                               const float* __restrict__ u1, const float* __restrict__ v1,
                                               const float* __restrict__ b0b, const float* __restrict__ b0p,
                                               const float* __restrict__ b1b, const float* __restrict__ b1p,
                                               const float* __restrict__ part, const float* __restrict__ sobj,
                                               const float* __restrict__ fcS, const float* __restrict__ fcO,
                                               float* __restrict__ tot, float* __restrict__ addS,
                                               float* __restrict__ addO,
                                               u16* __restrict__ totb, u16* __restrict__ aSb,
                                               u16* __restrict__ aOb) {
  int tt = blockIdx.x;
  int t = threadIdx.x;
  int d = t * 4;
  size_t rowoff = (size_t)tt * 512 + d;
  f32x4 u0r = *(const f32x4*)&u0[rowoff];
  f32x4 v0r = *(const f32x4*)&v0[rowoff];
  f32x4 u1r = *(const f32x4*)&u1[rowoff];
  f32x4 v1r = *(const f32x4*)&v1[rowoff];
  f32x4 B0B = *(const f32x4*)&b0b[d];
  f32x4 B0P = *(const f32x4*)&b0p[d];
  f32x4 B1B = *(const f32x4*)&b1b[d];
  f32x4 B1P = *(const f32x4*)&b1p[d];
  f32x4 srs = {0.f,0.f,0.f,0.f}, sro = {0.f,0.f,0.f,0.f};
  if (tt < 192) {
    #pragma unroll
    for (int c = 0; c < 4; c++) {
      srs += *(const f32x4*)&part[(((size_t)0 * 209 + tt) * 4 + c) * 512 + d];
      sro += *(const f32x4*)&part[(((size_t)1 * 209 + tt) * 4 + c) * 512 + d];
    }
    for (int o = 192; o < 209; o++) srs += relu4(B0P + u0r + *(const f32x4*)&v0[(size_t)o * 512 + d]);
    for (int s = 192; s < 209; s++) sro += relu4(B1P + *(const f32x4*)&u1[(size_t)s * 512 + d] + v1r);
    f32x4 qd0 = bf4(Q0 + ((size_t)tt * 193) * 512 + d);
    srs -= relu4(qd0 + u0r + v0r + B0B);
    f32x4 qd1 = bf4(Q1T + ((size_t)tt * 193) * 512 + d);
    sro -= relu4(qd1 + u1r + v1r + B1B);
  } else {
    for (int o = 0; o < 209; o++) srs += relu4(B0P + u0r + *(const f32x4*)&v0[(size_t)o * 512 + d]);
    srs -= relu4(B0P + u0r + v0r);
    for (int s = 0; s < 209; s++) sro += relu4(B1P + *(const f32x4*)&u1[(size_t)s * 512 + d] + v1r);
    sro -= relu4(B1P + u1r + v1r);
  }
  const float inv209 = 1.0f / (float)(209.0 + 1e-7);
  const float inv208 = 1.0f / (float)(208.0 + 1e-7);
  const float invrel = 0.5f / (float)(1.0 + 1e-7);
  f32x4 so4 = *(const f32x4*)&sobj[d] * inv209;
  srs *= inv208;
  sro *= inv208;
  f32x4 tt4 = *(const f32x4*)&tot[rowoff];
  tt4 += (so4 + srs + sro) * (1.0f / 3.0f);
  *(f32x4*)&tot[rowoff] = tt4;
  f32x4 aS = *(const f32x4*)&addS[rowoff] + *(const f32x4*)&fcS[rowoff] * invrel;
  f32x4 aO = *(const f32x4*)&addO[rowoff] + *(const f32x4*)&fcO[rowoff] * invrel;
  *(f32x4*)&addS[rowoff] = aS;
  *(f32x4*)&addO[rowoff] = aO;
  *(s16x4*)&totb[rowoff] = pack4(tt4);
  *(s16x4*)&aSb[rowoff]  = pack4(aS);
  *(s16x4*)&aOb[rowoff]  = pack4(aO);
}

// ================= kheads: out[192][9] =================
__global__ __launch_bounds__(256) void kheads(const float* __restrict__ tot,
    const float* __restrict__ w1a, const float* __restrict__ b1a, const float* __restrict__ w2a, const float* __restrict__ b2a,
    const float* __restrict__ w1b, const float* __restrict__ b1bb, const float* __restrict__ w2b, const float* __restrict__ b2b,
    const float* __restrict__ w1c, const float* __restrict__ b1c, const float* __restrict__ w2c, const float* __restrict__ b2c,
    float* __restrict__ out) {
  int row = blockIdx.x;
  int t = threadIdx.x;
  __shared__ float xs[512];
  xs[t] = tot[(size_t)row * 512 + t];
  xs[t + 256] = tot[(size_t)row * 512 + 256 + t];
  __syncthreads();
  const float* W1[3] = {w1a, w1b, w1c};
  const float* B1[3] = {b1a, b1bb, b1c};
  const float* W2[3] = {w2a, w2b, w2c};
  float p[9];
  #pragma unroll
  for (int hd = 0; hd < 3; hd++) {
    float a = B1[hd][t];
    for (int k = 0; k < 512; k += 4) {
      f32x4 x4 = *(const f32x4*)&xs[k];
      a = fmaf(x4.x, W1[hd][(size_t)(k + 0) * 256 + t], a);
      a = fmaf(x4.y, W1[hd][(size_t)(k + 1) * 256 + t], a);
      a = fmaf(x4.z, W1[hd][(size_t)(k + 2) * 256 + t], a);
      a = fmaf(x4.w, W1[hd][(size_t)(k + 3) * 256 + t], a);
    }
    float h = a > 0.f ? a : 0.2f * a;
    p[hd * 3 + 0] = h * W2[hd][t * 3 + 0];
    p[hd * 3 + 1] = h * W2[hd][t * 3 + 1];
    p[hd * 3 + 2] = h * W2[hd][t * 3 + 2];
  }
  __shared__ float red[9][256];
  #pragma unroll
  for (int c = 0; c < 9; c++) red[c][t] = p[c];
  __syncthreads();
  for (int s = 128; s > 0; s >>= 1) {
    if (t < s) {
      #pragma unroll
      for (int c = 0; c < 9; c++) red[c][t] += red[c][t + s];
    }
    __syncthreads();
  }
  if (t < 9) {
    const float* B2[3] = {b2a, b2b, b2c};
    out[(size_t)row * 9 + t] = red[t][0] + B2[t / 3][t % 3];
  }
}

extern "C" void kernel_launch(void* const* d_in, const int* in_sizes, int n_in,
                              void* d_out, int out_size, void* d_ws, size_t ws_size,
                              hipStream_t stream) {
  const float* xo  = (const float*)d_in[0];
  const float* xw  = (const float*)d_in[1];
  const float* xf  = (const float*)d_in[2];
  const float* xr  = (const float*)d_in[3];
  const float* ow1 = (const float*)d_in[4];
  const float* ob1 = (const float*)d_in[5];
  const float* ow2 = (const float*)d_in[6];
  const float* ob2 = (const float*)d_in[7];
  const float* ww1 = (const float*)d_in[8];
  const float* wb1 = (const float*)d_in[9];
  const float* ww2 = (const float*)d_in[10];
  const float* wb2 = (const float*)d_in[11];
  const float* fw1 = (const float*)d_in[12];
  const float* fb1 = (const float*)d_in[13];
  const float* fw2 = (const float*)d_in[14];
  const float* fb2 = (const float*)d_in[15];
  const float* rw1 = (const float*)d_in[16];
  const float* rb1 = (const float*)d_in[17];
  const float* rw2 = (const float*)d_in[18];
  const float* rb2 = (const float*)d_in[19];
  const float* cw  = (const float*)d_in[20];
  const float* cb  = (const float*)d_in[21];
  const float* tw1 = (const float*)d_in[22];
  const float* tb1 = (const float*)d_in[23];
  const float* tw2 = (const float*)d_in[24];
  const float* tb2 = (const float*)d_in[25];
  const float* ew1 = (const float*)d_in[26];
  const float* eb1 = (const float*)d_in[27];
  const float* ew2 = (const float*)d_in[28];
  const float* eb2 = (const float*)d_in[29];
  const float* sw1 = (const float*)d_in[30];
  const float* sb1 = (const float*)d_in[31];
  const float* sw2 = (const float*)d_in[32];
  const float* sb2 = (const float*)d_in[33];
  float* out = (float*)d_out;

  char* p = (char*)d_ws;
  auto alloc = [&](size_t bytes) { char* r = p; p += (bytes + 255) & ~(size_t)255; return r; };
  const size_t SZ = 209 * 512 * sizeof(float);
  const size_t BSZ = 256 * 512 * sizeof(u16);
  float* tot  = (float*)alloc(SZ);
  // --- contiguous zero block: addS, addO, totb, aSb, aOb ---
  float* addS = (float*)alloc(SZ);
  float* addO = (float*)alloc(SZ);
  u16*   totb = (u16*)alloc(BSZ);
  u16*   aSb  = (u16*)alloc(BSZ);
  u16*   aOb  = (u16*)alloc(BSZ);
  // ---------------------------------------------------------
  float* fc4part = (float*)alloc(4 * 512 * sizeof(float));
  float* fcS  = (float*)alloc(SZ);
  float* fcO  = (float*)alloc(SZ);
  float* u0   = (float*)alloc(SZ);
  float* v0   = (float*)alloc(SZ);
  float* u1   = (float*)alloc(SZ);
  float* v1   = (float*)alloc(SZ);
  float* hid  = (float*)alloc(SZ);
  float* sobj = (float*)alloc(512 * sizeof(float));
  float* part = (float*)alloc((size_t)2 * 209 * 4 * 512 * sizeof(float));
  float* b0b  = (float*)alloc(512 * sizeof(float));
  float* b0p  = (float*)alloc(512 * sizeof(float));
  float* b1b  = (float*)alloc(512 * sizeof(float));
  float* b1p  = (float*)alloc(512 * sizeof(float));
  u16* rw2b = (u16*)alloc((size_t)DD * sizeof(u16));
  u16* cwT  = (u16*)alloc((size_t)5 * DD * sizeof(u16));
  u16* Hh  = (u16*)alloc((size_t)36864 * 512 * sizeof(u16));
  u16* WcT = (u16*)alloc((size_t)1024 * 512 * sizeof(u16));
  u16* Q0  = (u16*)alloc((size_t)36864 * 512 * sizeof(u16));
  u16* Q1T = (u16*)alloc((size_t)36864 * 512 * sizeof(u16));

  hipMemsetAsync(addS, 0, 2 * SZ + 3 * BSZ, stream);

  PrepP pp;
  pp.xo = xo; pp.xw = xw; pp.xf = xf;
  pp.ow1 = ow1; pp.ob1 = ob1; pp.ww1 = ww1; pp.wb1 = wb1; pp.fw1 = fw1; pp.fb1 = fb1;
  pp.hid = hid;
  pp.rw2 = rw2; pp.rw2b = rw2b;
  pp.cw = cw; pp.cwT = cwT;
  pp.cb = cb; pp.rb2 = rb2;
  pp.b0b = b0b; pp.b0p = b0p; pp.b1b = b1b; pp.b1p = b1p;
  pp.xr = xr; pp.rw1 = rw1; pp.rb1 = rb1; pp.Hh = Hh;
  kprep<<<10841, 256, 0, stream>>>(pp);

  MidP mp{};
  mp.sj.j[0] = { hid,             ow2, ob2, tot,             totb,             192, 0 };
  mp.sj.j[1] = { hid + 192 * 512, ww2, wb2, tot + 192 * 512, totb + 192 * 512,  16, 0 };
  mp.sj.j[2] = { hid + 208 * 512, fw2, fb2, tot + 208 * 512, totb + 208 * 512,   1, 0 };
  mp.sj.njobs = 3;
  mp.sj.cum[0] = 0;
  for (int i = 0; i < 3; i++) mp.sj.cum[i + 1] = mp.sj.cum[i] + ((mp.sj.j[i].M + 31) / 32) * 8;
  mp.mj[0] = { rw2b, cwT,      WcT };
  mp.mj[1] = { rw2b, cwT + DD, WcT + DD };
  kmid<<<128, 256, 0, stream>>>(mp);

  kbig<<<2304, 256, 0, stream>>>(Hh, WcT, Q0, Q1T);

  MJobs st{};
  st.j[0] = { totb, cwT + 4 * DD, cb + 4 * 512, nullptr, fc4part, 209, 2 };
  st.j[1] = { totb, cwT + 2 * DD, cb + 2 * 512, fcS, nullptr, 209, 1 };
  st.j[2] = { totb, cwT + 3 * DD, cb + 3 * 512, fcO, nullptr, 209, 1 };
  st.j[3] = { aSb,  cwT,          nullptr,      u0,  nullptr, 209, 0 };
  st.j[4] = { aOb,  cwT,          nullptr,      v0,  nullptr, 209, 0 };
  st.j[5] = { aSb,  cwT + DD,     nullptr,      u1,  nullptr, 209, 0 };
  st.j[6] = { aOb,  cwT + DD,     nullptr,      v1,  nullptr, 209, 0 };
  st.njobs = 7;
  st.cum[0] = 0;
  for (int i = 0; i < 7; i++) st.cum[i + 1] = st.cum[i] + 4 * 8;  // 4 mtiles * 8 ntiles

  for (int step = 0; step < 4; step++) {
    kmg<<<st.cum[7], 256, 0, stream>>>(st);
    kpass<<<dim3(209, 4, 3), 128, 0, stream>>>(Q0, Q1T, u0, v0, u1, v1, b0b, b1b, fc4part, part, sobj);
    kfinish<<<209, 128, 0, stream>>>(Q0, Q1T, u0, v0, u1, v1, b0b, b0p, b1b, b1p,
                                     part, sobj, fcS, fcO, tot, addS, addO, totb, aSb, aOb);
  }

  kheads<<<192, 256, 0, stream>>>(tot, tw1, tb1, tw2, tb2, ew1, eb1, ew2, eb2, sw1, sb1, sw2, sb2, out);
}